// Round 1
// baseline (175.663 us; speedup 1.0000x reference)
//
#include <hip/hip_runtime.h>
#include <math.h>

#define BATCH 4096
#define NODES 256
#define FDIM  128
#define HID   16

// One block per batch element b (4096 blocks x 256 threads).
// Thread tid owns node n = tid. Weights a1[t] accessed uniformly -> s_loads.
__launch_bounds__(256, 4)
__global__ void mta_kernel(const float* __restrict__ x,
                           const float* __restrict__ a1,
                           const float* __restrict__ a2,
                           const float* __restrict__ adj,
                           const int*  __restrict__ node_index,
                           const int*  __restrict__ type_index,
                           float* __restrict__ out) {
    const int b   = blockIdx.x;
    const int tid = threadIdx.x;

    // Block-uniform scalars (force SGPR so weight loads become s_load)
    const int t  = __builtin_amdgcn_readfirstlane(type_index[b]);
    const int ni = __builtin_amdgcn_readfirstlane(node_index[0]);

    const float* At  = a1 + (size_t)t * (2 * FDIM * HID); // top  [FDIM][HID]
    const float* Ab  = At + FDIM * HID;                   // bottom [FDIM][HID]
    const float* a2t = a2 + t * HID;

    __shared__ float part[16][17];  // c0 partials (pad to avoid conflicts)
    __shared__ float c0s[16];
    __shared__ float redm[4];
    __shared__ float reds[4];

    // ---- c0[h] = sum_f x[b,ni,f] * At[f][h], computed cooperatively ----
    {
        const float* x0 = x + ((size_t)b * NODES + ni) * FDIM;
        int f2 = tid >> 4;       // 16 f-groups of 8
        int h  = tid & 15;
        float p = 0.f;
        #pragma unroll
        for (int j = 0; j < 8; ++j) {
            int f = f2 * 8 + j;
            p = fmaf(x0[f], At[f * HID + h], p);
        }
        part[f2][h] = p;
    }
    __syncthreads();
    if (tid < 16) {
        float s = 0.f;
        #pragma unroll
        for (int g = 0; g < 16; ++g) s += part[g][tid];
        c0s[tid] = s;
    }
    __syncthreads();

    // ---- main: acc[h] = sum_f x[b,n,f] * Ab[f][h] ----
    const float* xr = x + ((size_t)b * NODES + tid) * FDIM;
    float acc[16];
    #pragma unroll
    for (int h = 0; h < 16; ++h) acc[h] = 0.f;

    #pragma unroll 2
    for (int f4 = 0; f4 < FDIM / 4; ++f4) {
        const float4 xv = *reinterpret_cast<const float4*>(xr + f4 * 4);
        const float* Af = Ab + f4 * 4 * HID;   // uniform address -> s_load
        #pragma unroll
        for (int j = 0; j < 4; ++j) {
            const float xj = (j == 0) ? xv.x : (j == 1) ? xv.y : (j == 2) ? xv.z : xv.w;
            #pragma unroll
            for (int h = 0; h < 16; ++h)
                acc[h] = fmaf(xj, Af[j * HID + h], acc[h]);
        }
    }

    // ---- e = lrelu( sum_h lrelu(acc+c0) * a2t ) ----
    float e = 0.f;
    #pragma unroll
    for (int h = 0; h < 16; ++h) {
        float v = acc[h] + c0s[h];
        v = (v > 0.f) ? v : 0.01f * v;
        e = fmaf(v, a2t[h], e);
    }
    e = (e > 0.f) ? e : 0.01f * e;

    // ---- masked softmax over the 256 nodes of this block ----
    const float m   = adj[tid];
    float       val = (m > 0.f) ? e : -INFINITY;

    float mx = val;
    #pragma unroll
    for (int off = 32; off; off >>= 1) mx = fmaxf(mx, __shfl_xor(mx, off));
    const int wid = tid >> 6;
    if ((tid & 63) == 0) redm[wid] = mx;
    __syncthreads();
    mx = fmaxf(fmaxf(redm[0], redm[1]), fmaxf(redm[2], redm[3]));

    float p = (m > 0.f) ? __expf(e - mx) : 0.f;
    float s = p;
    #pragma unroll
    for (int off = 32; off; off >>= 1) s += __shfl_xor(s, off);
    if ((tid & 63) == 0) reds[wid] = s;
    __syncthreads();
    const float Z = reds[0] + reds[1] + reds[2] + reds[3];

    out[(size_t)b * NODES + tid] = p / Z;
}

extern "C" void kernel_launch(void* const* d_in, const int* in_sizes, int n_in,
                              void* d_out, int out_size, void* d_ws, size_t ws_size,
                              hipStream_t stream) {
    const float* x   = (const float*)d_in[0];
    const float* a1  = (const float*)d_in[1];
    const float* a2  = (const float*)d_in[2];
    const float* adj = (const float*)d_in[3];
    const int*   ni  = (const int*)d_in[4];
    const int*   ti  = (const int*)d_in[5];
    float* out = (float*)d_out;

    mta_kernel<<<BATCH, NODES, 0, stream>>>(x, a1, a2, adj, ni, ti, out);
}